// Round 4
// baseline (263.815 us; speedup 1.0000x reference)
//
#include <hip/hip_runtime.h>

// QuantizedLinear: out[64,11008] = x[64,4096] @ (Wq*scale)^T + bias
// v5: counted-vmcnt double-buffered gload_lds pipeline (T3/T4 minimum recipe).
// v4 post-mortem: full-drain (__syncthreads -> vmcnt(0)) per 48KB tile waits on
// tail latency of 768 loads with zero new issue -> ~4.5 TB/s weight stream.
// v5: BK=64 tiles (24KB), 2 LDS buffers (48KB -> 3 blocks/CU), issue tile t+1's
// 6 gload_lds BEFORE s_waitcnt vmcnt(6) + raw s_barrier -> wait only on the
// OLDER tile while the newer streams. Scale load moved post-loop (keeps vmcnt
// count exact). xcvt + bias-init fused into one prep launch.
// Model: dur_us = ~210-215 us fixed harness reset (688 MiB poison fills at 85%
// HBM peak, every top-5 entry) + ours (~45-50 at v4). Target ours ~37.

#define M_DIM 64
#define N_DIM 11008
#define K_DIM 4096
#define KSPLIT 8
#define KC (K_DIM / KSPLIT)   // 512
#define BK 64                 // k per staged tile
#define NT (KC / BK)          // 8 tiles per block
#define BLOCK_N 64            // 4 waves x 16 N each
#define WBYTES (64 * 256)     // weight buffer: 64 rows x 64 int32 = 16 KB
#define XBYTES (64 * 128)     // x buffer: 64 rows x 64 bf16 = 8 KB
#define BUFB (WBYTES + XBYTES)  // 24576

typedef __attribute__((ext_vector_type(8))) short bf16x8;
typedef __attribute__((ext_vector_type(8))) short s16x8;
typedef __attribute__((ext_vector_type(4))) float f32x4;
typedef __attribute__((ext_vector_type(4))) int i32x4;
typedef __attribute__((ext_vector_type(4))) short s16x4;

// int in [-128,127] -> bf16 is EXACT: cvt to f32, truncate mantissa
__device__ __forceinline__ short i2bf(int q) {
    float f = (float)q;
    return (short)(__builtin_bit_cast(unsigned int, f) >> 16);
}

// RNE float -> bf16
__device__ __forceinline__ short f2bf(float f) {
    unsigned int u = __builtin_bit_cast(unsigned int, f);
    u = u + 0x7FFFu + ((u >> 16) & 1u);
    return (short)(u >> 16);
}

// async global->LDS, 16 B per lane. LDS dest: wave-uniform base + lane*16.
__device__ __forceinline__ void load_lds_16B(const void* g, void* l) {
    __builtin_amdgcn_global_load_lds(
        (const __attribute__((address_space(1))) unsigned int*)g,
        (__attribute__((address_space(3))) unsigned int*)l,
        16, 0, 0);
}

// ---- prep: x f32->bf16 (blocks 0..127) + out=bias broadcast (blocks 128..815) ----
__global__ __launch_bounds__(256) void prep_kernel(const float* __restrict__ x,
                                                   const float* __restrict__ bias,
                                                   short* __restrict__ xbf,
                                                   float* __restrict__ out) {
    int b = blockIdx.x;
    if (b < 128) {
        int idx = (b * 256 + threadIdx.x) * 8;
        f32x4 a = *(const f32x4*)(x + idx);
        f32x4 c = *(const f32x4*)(x + idx + 4);
        s16x8 h;
        h[0] = f2bf(a.x); h[1] = f2bf(a.y); h[2] = f2bf(a.z); h[3] = f2bf(a.w);
        h[4] = f2bf(c.x); h[5] = f2bf(c.y); h[6] = f2bf(c.z); h[7] = f2bf(c.w);
        *(s16x8*)(xbf + idx) = h;
    } else {
        int idx = (b - 128) * 256 + threadIdx.x;   // float4 index over out
        int col4 = idx % 2752;                     // N/4
        f32x4 v = *(const f32x4*)(bias + col4 * 4);
        *(f32x4*)(out + (size_t)idx * 4) = v;
    }
}

// ---- stage one BK=64 tile: 4 weight + 2 x gload_lds per wave (6 VMEM) ----
// LDS layout: weights [row][256B] then x [row][128B], XOR-swizzled byte^=(row&7)<<4
// applied on the GLOBAL source (gload_lds dest must be linear; rule 21).
__device__ __forceinline__ void stage_tile(const int* __restrict__ wq,
                                           const short* __restrict__ xbf,
                                           char* buf, int n0, int kA,
                                           int wave, int lane) {
    char* wl = buf;
    char* xl = buf + WBYTES;
    #pragma unroll
    for (int j = 0; j < 4; ++j) {                  // 4 rows/instr, 16 lanes x 16B per row
        int row  = wave * 16 + j * 4 + (lane >> 4);
        int colb = ((lane & 15) * 16) ^ ((row & 7) << 4);
        const char* g = (const char*)(wq + (size_t)(n0 + row) * K_DIM + kA) + colb;
        load_lds_16B(g, wl + (wave * 16 + j * 4) * 256);
    }
    #pragma unroll
    for (int j = 0; j < 2; ++j) {                  // 8 rows/instr, 8 lanes x 16B per row
        int row  = wave * 16 + j * 8 + (lane >> 3);
        int colb = ((lane & 7) * 16) ^ ((row & 7) << 4);
        const char* g = (const char*)(xbf + (size_t)row * K_DIM + kA) + colb;
        load_lds_16B(g, xl + (wave * 16 + j * 8) * 128);
    }
}

// ---- compute one BK=64 tile: 2 k-steps x 4 mi MFMA ----
__device__ __forceinline__ void compute_tile(const char* buf, f32x4 acc[4],
                                             int wave, int quad, int l16) {
    const char* wl = buf;
    const char* xl = buf + WBYTES;
    const int wrow = wave * 16 + l16;
    const int wsw  = (wrow & 7) << 4;
    #pragma unroll
    for (int kk = 0; kk < BK; kk += 32) {
        const int L0 = (kk + quad * 8) * 4;        // logical byte in 256B weight row
        i32x4 b0 = *(const i32x4*)(wl + wrow * 256 + ((L0)      ^ wsw));
        i32x4 b1 = *(const i32x4*)(wl + wrow * 256 + ((L0 + 16) ^ wsw));
        bf16x8 bfrag;
        bfrag[0] = i2bf(b0.x); bfrag[1] = i2bf(b0.y);
        bfrag[2] = i2bf(b0.z); bfrag[3] = i2bf(b0.w);
        bfrag[4] = i2bf(b1.x); bfrag[5] = i2bf(b1.y);
        bfrag[6] = i2bf(b1.z); bfrag[7] = i2bf(b1.w);
        #pragma unroll
        for (int mi = 0; mi < 4; ++mi) {
            const int arow = mi * 16 + l16;
            const int La   = (kk + quad * 8) * 2;  // logical byte in 128B x row
            bf16x8 afrag = *(const bf16x8*)(xl + arow * 128 + (La ^ ((arow & 7) << 4)));
            acc[mi] = __builtin_amdgcn_mfma_f32_16x16x32_bf16(afrag, bfrag, acc[mi], 0, 0, 0);
        }
    }
}

// ---- v5 GEMM: dbuf pipeline, counted vmcnt, raw barriers, atomic K-split ----
__global__ __launch_bounds__(256) void qlinear_v5_kernel(const short* __restrict__ xbf,
                                                         const int* __restrict__ wq,
                                                         const float* __restrict__ scale_p,
                                                         float* __restrict__ out) {
    __shared__ char smem[2 * BUFB];   // 48 KB -> 3 blocks/CU

    const int tid  = threadIdx.x;
    const int wave = tid >> 6;
    const int lane = tid & 63;
    const int quad = lane >> 4;
    const int l16  = lane & 15;

    const int n0  = blockIdx.x * BLOCK_N;
    const int kc0 = blockIdx.y * KC;

    f32x4 acc[4] = {f32x4{0,0,0,0}, f32x4{0,0,0,0}, f32x4{0,0,0,0}, f32x4{0,0,0,0}};

    // prologue: stage tile 0
    stage_tile(wq, xbf, smem, n0, kc0, wave, lane);

    // steady state: stage t+1, wait only for tile t (vmcnt(6): 6 newer in flight)
    for (int t = 0; t < NT - 1; ++t) {
        char* cur = smem + (t & 1) * BUFB;
        char* nxt = smem + ((t + 1) & 1) * BUFB;
        stage_tile(wq, xbf, nxt, n0, kc0 + (t + 1) * BK, wave, lane);
        asm volatile("s_waitcnt vmcnt(6)" ::: "memory");
        __builtin_amdgcn_sched_barrier(0);
        __builtin_amdgcn_s_barrier();            // all waves: tile t resident
        compute_tile(cur, acc, wave, quad, l16);
        __builtin_amdgcn_sched_barrier(0);
        __builtin_amdgcn_s_barrier();            // all waves done reading cur
    }
    // epilogue tile
    asm volatile("s_waitcnt vmcnt(0)" ::: "memory");
    __builtin_amdgcn_sched_barrier(0);
    __builtin_amdgcn_s_barrier();
    compute_tile(smem + ((NT - 1) & 1) * BUFB, acc, wave, quad, l16);

    // ---- epilogue: scale + atomic accumulate (K-split partials) ----
    const float scale = *scale_p;
    const int nout = n0 + wave * 16 + l16;
    #pragma unroll
    for (int mi = 0; mi < 4; ++mi) {
        #pragma unroll
        for (int r = 0; r < 4; ++r) {
            int m = mi * 16 + quad * 4 + r;
            atomicAdd(&out[(size_t)m * N_DIM + nout], acc[mi][r] * scale);
        }
    }
}

// ---------------------------------------------------------------------------
// Fallback (round-0 verified): reg-loaded weights + LDS-staged x + atomics.
// ---------------------------------------------------------------------------
#define LDS_STRIDE 136
#define FB_BK 128

__global__ __launch_bounds__(256) void init_bias_kernel(const float* __restrict__ bias,
                                                        float* __restrict__ out) {
    int idx = blockIdx.x * 256 + threadIdx.x;
    int col4 = idx % 2752;
    f32x4 b = *(const f32x4*)(bias + col4 * 4);
    *(f32x4*)(out + (size_t)idx * 4) = b;
}

__global__ __launch_bounds__(256) void qlinear_atomic_kernel(const float* __restrict__ x,
                                                             const int* __restrict__ wq,
                                                             const float* __restrict__ scale_p,
                                                             float* __restrict__ out) {
    __shared__ short lds[M_DIM * LDS_STRIDE];

    const int tid  = threadIdx.x;
    const int wave = tid >> 6;
    const int lane = tid & 63;
    const int quad = lane >> 4;
    const int l16  = lane & 15;

    const int n0  = blockIdx.x * BLOCK_N;
    const int kc0 = blockIdx.y * KC;
    const float scale = *scale_p;

    const int nw = n0 + wave * 16 + l16;
    const int* wptr = wq + (size_t)nw * K_DIM + kc0 + quad * 8;

    f32x4 acc[4] = {f32x4{0,0,0,0}, f32x4{0,0,0,0}, f32x4{0,0,0,0}, f32x4{0,0,0,0}};

    for (int kb = 0; kb < KC; kb += FB_BK) {
        {
            const float* xbase = x + kc0 + kb;
            #pragma unroll
            for (int j = 0; j < 8; ++j) {
                int f  = tid + j * 256;
                int row = f >> 5;
                int c4  = f & 31;
                f32x4 v = *(const f32x4*)(xbase + (size_t)row * K_DIM + c4 * 4);
                s16x4 h;
                h.x = f2bf(v.x); h.y = f2bf(v.y); h.z = f2bf(v.z); h.w = f2bf(v.w);
                *(s16x4*)&lds[row * LDS_STRIDE + c4 * 4] = h;
            }
        }
        __syncthreads();

        #pragma unroll
        for (int kk = 0; kk < FB_BK; kk += 32) {
            i32x4 b0 = *(const i32x4*)(wptr + kb + kk);
            i32x4 b1 = *(const i32x4*)(wptr + kb + kk + 4);
            bf16x8 bfrag;
            bfrag[0] = i2bf(b0.x); bfrag[1] = i2bf(b0.y);
            bfrag[2] = i2bf(b0.z); bfrag[3] = i2bf(b0.w);
            bfrag[4] = i2bf(b1.x); bfrag[5] = i2bf(b1.y);
            bfrag[6] = i2bf(b1.z); bfrag[7] = i2bf(b1.w);

            #pragma unroll
            for (int mi = 0; mi < 4; ++mi) {
                bf16x8 afrag = *(const bf16x8*)&lds[(mi * 16 + l16) * LDS_STRIDE + kk + quad * 8];
                acc[mi] = __builtin_amdgcn_mfma_f32_16x16x32_bf16(afrag, bfrag, acc[mi], 0, 0, 0);
            }
        }
        __syncthreads();
    }

    const int nout = n0 + wave * 16 + l16;
    #pragma unroll
    for (int mi = 0; mi < 4; ++mi) {
        #pragma unroll
        for (int r = 0; r < 4; ++r) {
            int m = mi * 16 + quad * 4 + r;
            atomicAdd(&out[(size_t)m * N_DIM + nout], acc[mi][r] * scale);
        }
    }
}

extern "C" void kernel_launch(void* const* d_in, const int* in_sizes, int n_in,
                              void* d_out, int out_size, void* d_ws, size_t ws_size,
                              hipStream_t stream) {
    const float* x      = (const float*)d_in[0];
    const int*   wq     = (const int*)d_in[1];
    const float* scale  = (const float*)d_in[2];
    const float* bias   = (const float*)d_in[3];
    float* out = (float*)d_out;

    const size_t xbf_bytes = (size_t)M_DIM * K_DIM * sizeof(short);  // 512 KB
    dim3 grid(N_DIM / BLOCK_N, KSPLIT);  // (172, 8)

    if (ws_size >= xbf_bytes && d_ws != nullptr) {
        short* xbf = (short*)d_ws;
        // 1) fused prep: xcvt (128 blocks) + bias-init (688 blocks)
        prep_kernel<<<816, 256, 0, stream>>>(x, bias, xbf, out);
        // 2) pipelined GEMM
        qlinear_v5_kernel<<<grid, 256, 0, stream>>>(xbf, wq, scale, out);
    } else {
        init_bias_kernel<<<688, 256, 0, stream>>>(bias, out);
        qlinear_atomic_kernel<<<grid, 256, 0, stream>>>(x, wq, scale, out);
    }
}